// Round 5
// baseline (213.934 us; speedup 1.0000x reference)
//
#include <hip/hip_runtime.h>

// QKVAttention: qkv [8, 3072, 1024] fp32 -> out [8, 1024, 1024] fp32
// R5: barrier-free flash loop. Prepass converts only K (transposed [s][c]) and
// V ([c][s]) to fp16 in d_ws; attention kernel loads K/V MFMA fragments
// DIRECTLY from global (L2-resident, 16B/lane contiguous) and uses LDS only
// for the wave-local P layout round-trip. Q is gathered once per block from
// the raw fp32 input. Zero __syncthreads in the hot loop.

typedef __attribute__((ext_vector_type(8))) _Float16 f16x8;
typedef __attribute__((ext_vector_type(4))) _Float16 f16x4;
typedef __attribute__((ext_vector_type(4))) float f32x4;

#define K_OFF      0
#define V_OFF      8388608         // halves: 128*1024*64
#define WS_BYTES   33554432        // 32 MB (K + V fp16)
#define QSCALE     (0.125f * 1.44269504f)   // scale^2 * log2(e), folded into Q

// ---------------- Pre-pass ----------------
// bid < 2048:  K tile  -> ws[K_OFF + head*65536 + s*64 + c]   (transpose via LDS)
// bid >= 2048: V rows  -> ws[V_OFF + head*65536 + c*1024 + s] (straight convert)
__global__ __launch_bounds__(256) void prepass_kernel(
    const float* __restrict__ qkv, _Float16* __restrict__ ws) {
    const int tid = threadIdx.x;
    const int bid = blockIdx.x;
    if (bid < 2048) {
        __shared__ float ft[64][68];
        const int head = bid >> 4;
        const int blk  = bid & 15;
        const int b = head >> 4, h = head & 15;
        const int s0 = blk * 64;
        const float* src = qkv + ((size_t)b * 3072 + 1024 + h * 64) * 1024;
#pragma unroll
        for (int i = 0; i < 4; ++i) {
            const int c = i * 16 + (tid >> 4);
            const int s = (tid & 15) * 4;
            const float4 v = *(const float4*)(src + (size_t)c * 1024 + s0 + s);
            ft[s + 0][c] = v.x;
            ft[s + 1][c] = v.y;
            ft[s + 2][c] = v.z;
            ft[s + 3][c] = v.w;
        }
        __syncthreads();
        _Float16* dst = ws + K_OFF + (size_t)head * 65536 + (size_t)s0 * 64;
#pragma unroll
        for (int r = 0; r < 2; ++r) {
            const int g = r * 256 + tid;
            const int s = g >> 3, cb = g & 7;
            const float4 a  = *(const float4*)&ft[s][cb * 8];
            const float4 b4 = *(const float4*)&ft[s][cb * 8 + 4];
            f16x8 o = { (_Float16)a.x,  (_Float16)a.y,  (_Float16)a.z,  (_Float16)a.w,
                        (_Float16)b4.x, (_Float16)b4.y, (_Float16)b4.z, (_Float16)b4.w };
            *(f16x8*)(dst + (size_t)s * 64 + cb * 8) = o;
        }
    } else {
        const int idx  = bid - 2048;
        const int head = idx >> 4;
        const int blk  = idx & 15;           // 4 c-rows per block
        const int b = head >> 4, h = head & 15;
        const int c = blk * 4 + (tid >> 6);
        const int s = (tid & 63) * 16;
        const float* src = qkv + ((size_t)b * 3072 + 2048 + h * 64 + c) * 1024 + s;
        _Float16* dst = ws + V_OFF + (size_t)head * 65536 + (size_t)c * 1024 + s;
#pragma unroll
        for (int j = 0; j < 2; ++j) {
            const float4 a  = *(const float4*)(src + j * 8);
            const float4 b4 = *(const float4*)(src + j * 8 + 4);
            f16x8 o = { (_Float16)a.x,  (_Float16)a.y,  (_Float16)a.z,  (_Float16)a.w,
                        (_Float16)b4.x, (_Float16)b4.y, (_Float16)b4.z, (_Float16)b4.w };
            *(f16x8*)(dst + j * 8) = o;
        }
    }
}

// ---------------- Main flash kernel: no barriers in the loop ----------------
__launch_bounds__(256, 2)
__global__ void attn_kernel(const float* __restrict__ qkv,
                            const _Float16* __restrict__ ws,
                            float* __restrict__ out) {
    __shared__ __align__(16) _Float16 P[256][72];   // wave-private row blocks

    const int tid  = threadIdx.x;
    const int wv   = tid >> 6;
    const int lane = tid & 63;
    const int li   = lane & 15;
    const int quad = lane >> 4;

    const int bid  = blockIdx.x;
    const int head = (bid >> 5) * 8 + (bid & 7);  // head's 4 t-tiles share an XCD
    const int tt   = (bid >> 3) & 3;
    const int t0   = tt * 256;
    const int b = head >> 4, h = head & 15;

    const _Float16* kt = ws + K_OFF + (size_t)head * 65536;
    const _Float16* vh = ws + V_OFF + (size_t)head * 65536;
    const float*    qb = qkv + ((size_t)b * 3072 + h * 64) * 1024;

    // ---- One-time Q fragment gather (B-operand: n=t, k=c), scale folded ----
    f16x8 bq[4][2];
#pragma unroll
    for (int sub = 0; sub < 4; ++sub) {
        const int t = t0 + wv * 64 + sub * 16 + li;
#pragma unroll
        for (int kk = 0; kk < 2; ++kk) {
            union { f16x8 v; _Float16 e[8]; } u;
#pragma unroll
            for (int j = 0; j < 8; ++j) {
                const int c = kk * 32 + quad * 8 + j;
                u.e[j] = (_Float16)(qb[(size_t)c * 1024 + t] * QSCALE);
            }
            bq[sub][kk] = u.v;
        }
    }

    f32x4 accz[4][4] = {};     // [sub][nc]
    float psum[4] = {};

    for (int si = 0; si < 16; ++si) {
        const int s0 = si * 64;

        // ---- K fragments direct from global (A: m=s, k=c) ----
        f16x8 kf[4][2];
#pragma unroll
        for (int ns = 0; ns < 4; ++ns)
#pragma unroll
            for (int kk = 0; kk < 2; ++kk)
                kf[ns][kk] = *(const f16x8*)&kt[(size_t)(s0 + ns * 16 + li) * 64
                                                + kk * 32 + quad * 8];
        // ---- V fragments direct from global (B: n=c, k=s) ----
        f16x8 vf[2][4];
#pragma unroll
        for (int kk = 0; kk < 2; ++kk)
#pragma unroll
            for (int nc = 0; nc < 4; ++nc)
                vf[kk][nc] = *(const f16x8*)&vh[(size_t)(nc * 16 + li) * 1024
                                                + s0 + kk * 32 + quad * 8];

        // ---- S^T = K Q^T ; exp2 ; pack P wide (wave-local) ----
#pragma unroll
        for (int ns = 0; ns < 4; ++ns) {
#pragma unroll
            for (int sub = 0; sub < 4; ++sub) {
                f32x4 st = {};
                st = __builtin_amdgcn_mfma_f32_16x16x32_f16(kf[ns][0], bq[sub][0], st, 0, 0, 0);
                st = __builtin_amdgcn_mfma_f32_16x16x32_f16(kf[ns][1], bq[sub][1], st, 0, 0, 0);
                const float p0 = __builtin_amdgcn_exp2f(st[0]);
                const float p1 = __builtin_amdgcn_exp2f(st[1]);
                const float p2 = __builtin_amdgcn_exp2f(st[2]);
                const float p3 = __builtin_amdgcn_exp2f(st[3]);
                psum[sub] += (p0 + p1) + (p2 + p3);
                f16x4 pk = { (_Float16)p0, (_Float16)p1, (_Float16)p2, (_Float16)p3 };
                *(f16x4*)&P[wv * 64 + sub * 16 + li][ns * 16 + quad * 4] = pk;
            }
        }

        // ---- Z^T += P V^T (P round-trip wave-local: no barrier) ----
#pragma unroll
        for (int kk = 0; kk < 2; ++kk) {
            f16x8 ap[4];
#pragma unroll
            for (int sub = 0; sub < 4; ++sub)
                ap[sub] = *(const f16x8*)&P[wv * 64 + sub * 16 + li][kk * 32 + quad * 8];
#pragma unroll
            for (int nc = 0; nc < 4; ++nc)
#pragma unroll
                for (int sub = 0; sub < 4; ++sub)
                    accz[sub][nc] = __builtin_amdgcn_mfma_f32_16x16x32_f16(
                        ap[sub], vf[kk][nc], accz[sub][nc], 0, 0, 0);
        }
    }

    // ---- Denominators: cross-quad reduce + redistribute ----
    float rl[4][4];
#pragma unroll
    for (int sub = 0; sub < 4; ++sub) {
        float s = psum[sub];
        s += __shfl_xor(s, 16);
        s += __shfl_xor(s, 32);
#pragma unroll
        for (int r = 0; r < 4; ++r)
            rl[sub][r] = 1.0f / __shfl(s, quad * 4 + r);
    }

    // ---- Store: D^T rows contiguous in t -> direct float4 stores ----
    float* obase = out + (size_t)b * 1024 * 1024 + (size_t)(h * 64) * 1024 + t0;
#pragma unroll
    for (int sub = 0; sub < 4; ++sub)
#pragma unroll
        for (int nc = 0; nc < 4; ++nc) {
            const int c = nc * 16 + li;
            const int t = wv * 64 + sub * 16 + quad * 4;
            f32x4 z = accz[sub][nc];
            float4 o = { z[0] * rl[sub][0], z[1] * rl[sub][1],
                         z[2] * rl[sub][2], z[3] * rl[sub][3] };
            *(float4*)(obase + (size_t)c * 1024 + t) = o;
        }
}

// ---------------- Fallback (single-kernel path, ws too small) ----------------
typedef __attribute__((ext_vector_type(4))) _Float16 f16x4_t;
struct S1fb {
    _Float16 K[64][72];
    _Float16 V[64][72];
    _Float16 P[128][72];
};
union SMemFb {
    S1fb s1;
    float zt[64][132];
};

__launch_bounds__(256, 4)
__global__ void qkv_attn_fallback(const float* __restrict__ qkv,
                                  float* __restrict__ out) {
    constexpr int L = 1024;
    __shared__ SMemFb sm;
    const int tid  = threadIdx.x;
    const int wv   = tid >> 6;
    const int lane = tid & 63;
    const int li   = lane & 15;
    const int quad = lane >> 4;
    const int bid  = blockIdx.x;
    const int head = (bid >> 6) * 8 + (bid & 7);
    const int tt   = (bid >> 3) & 7;
    const int b = head >> 4;
    const int h = head & 15;
    const float* qbase = qkv + (size_t)b * 3072 * L + (size_t)(h * 64) * L;
    const float* kbase = qbase + (size_t)1024 * L;
    const float* vbase = qbase + (size_t)2048 * L;
    float*       obase = out + (size_t)b * 1024 * L + (size_t)(h * 64) * L;
    const int t0 = tt * 128;
#pragma unroll
    for (int i = 0; i < 4; ++i) {
        const int c = i * 16 + (tid >> 4);
        const int t = (tid & 15) * 8;
        const float4 qa = *(const float4*)(qbase + (size_t)c * L + t0 + t);
        const float4 qb = *(const float4*)(qbase + (size_t)c * L + t0 + t + 4);
        sm.s1.P[t + 0][c] = (_Float16)(qa.x * 0.125f);
        sm.s1.P[t + 1][c] = (_Float16)(qa.y * 0.125f);
        sm.s1.P[t + 2][c] = (_Float16)(qa.z * 0.125f);
        sm.s1.P[t + 3][c] = (_Float16)(qa.w * 0.125f);
        sm.s1.P[t + 4][c] = (_Float16)(qb.x * 0.125f);
        sm.s1.P[t + 5][c] = (_Float16)(qb.y * 0.125f);
        sm.s1.P[t + 6][c] = (_Float16)(qb.z * 0.125f);
        sm.s1.P[t + 7][c] = (_Float16)(qb.w * 0.125f);
    }
    __syncthreads();
    f16x8 aq0[2], aq1[2];
#pragma unroll
    for (int kk = 0; kk < 2; ++kk) {
        aq0[kk] = *(const f16x8*)&sm.s1.P[wv * 32 + li][kk * 32 + quad * 8];
        aq1[kk] = *(const f16x8*)&sm.s1.P[wv * 32 + 16 + li][kk * 32 + quad * 8];
    }
    f32x4 accz0[4] = {}, accz1[4] = {};
    float psum0[4] = {}, psum1[4] = {};
    float4 kreg[4], vreg[4];
#pragma unroll
    for (int i = 0; i < 4; ++i) {
        const int c = i * 16 + (tid >> 4);
        const int s = (tid & 15) * 4;
        kreg[i] = *(const float4*)(kbase + (size_t)c * L + s);
        vreg[i] = *(const float4*)(vbase + (size_t)c * L + s);
    }
    for (int si = 0; si < 16; ++si) {
        __syncthreads();
#pragma unroll
        for (int i = 0; i < 4; ++i) {
            const int c = i * 16 + (tid >> 4);
            const int s = (tid & 15) * 4;
            sm.s1.K[s + 0][c] = (_Float16)kreg[i].x;
            sm.s1.K[s + 1][c] = (_Float16)kreg[i].y;
            sm.s1.K[s + 2][c] = (_Float16)kreg[i].z;
            sm.s1.K[s + 3][c] = (_Float16)kreg[i].w;
            f16x4_t pv = { (_Float16)vreg[i].x, (_Float16)vreg[i].y,
                           (_Float16)vreg[i].z, (_Float16)vreg[i].w };
            *(f16x4_t*)&sm.s1.V[c][s] = pv;
        }
        __syncthreads();
        if (si < 15) {
            const int s0n = (si + 1) * 64;
#pragma unroll
            for (int i = 0; i < 4; ++i) {
                const int c = i * 16 + (tid >> 4);
                const int s = (tid & 15) * 4;
                kreg[i] = *(const float4*)(kbase + (size_t)c * L + s0n + s);
                vreg[i] = *(const float4*)(vbase + (size_t)c * L + s0n + s);
            }
        }
#pragma unroll
        for (int nt = 0; nt < 4; ++nt) {
            f32x4 a0 = {}, a1 = {};
#pragma unroll
            for (int kk = 0; kk < 2; ++kk) {
                f16x8 bk = *(const f16x8*)&sm.s1.K[nt * 16 + li][kk * 32 + quad * 8];
                a0 = __builtin_amdgcn_mfma_f32_16x16x32_f16(aq0[kk], bk, a0, 0, 0, 0);
                a1 = __builtin_amdgcn_mfma_f32_16x16x32_f16(aq1[kk], bk, a1, 0, 0, 0);
            }
#pragma unroll
            for (int r = 0; r < 4; ++r) {
                const float p0 = __expf(a0[r]);
                const float p1 = __expf(a1[r]);
                psum0[r] += p0;
                psum1[r] += p1;
                sm.s1.P[wv * 32 + quad * 4 + r][nt * 16 + li] = (_Float16)p0;
                sm.s1.P[wv * 32 + 16 + quad * 4 + r][nt * 16 + li] = (_Float16)p1;
            }
        }
#pragma unroll
        for (int kk = 0; kk < 2; ++kk) {
            f16x8 ap0 = *(const f16x8*)&sm.s1.P[wv * 32 + li][kk * 32 + quad * 8];
            f16x8 ap1 = *(const f16x8*)&sm.s1.P[wv * 32 + 16 + li][kk * 32 + quad * 8];
#pragma unroll
            for (int nt = 0; nt < 4; ++nt) {
                f16x8 bv = *(const f16x8*)&sm.s1.V[nt * 16 + li][kk * 32 + quad * 8];
                accz0[nt] = __builtin_amdgcn_mfma_f32_16x16x32_f16(ap0, bv, accz0[nt], 0, 0, 0);
                accz1[nt] = __builtin_amdgcn_mfma_f32_16x16x32_f16(ap1, bv, accz1[nt], 0, 0, 0);
            }
        }
    }
    float rl0[4], rl1[4];
#pragma unroll
    for (int r = 0; r < 4; ++r) {
        float s0 = psum0[r], s1 = psum1[r];
        s0 += __shfl_xor(s0, 1); s0 += __shfl_xor(s0, 2);
        s0 += __shfl_xor(s0, 4); s0 += __shfl_xor(s0, 8);
        s1 += __shfl_xor(s1, 1); s1 += __shfl_xor(s1, 2);
        s1 += __shfl_xor(s1, 4); s1 += __shfl_xor(s1, 8);
        rl0[r] = 1.0f / s0;
        rl1[r] = 1.0f / s1;
    }
    __syncthreads();
#pragma unroll
    for (int nt = 0; nt < 4; ++nt)
#pragma unroll
        for (int r = 0; r < 4; ++r) {
            sm.zt[nt * 16 + li][wv * 32 + quad * 4 + r]      = accz0[nt][r] * rl0[r];
            sm.zt[nt * 16 + li][wv * 32 + 16 + quad * 4 + r] = accz1[nt][r] * rl1[r];
        }
    __syncthreads();
#pragma unroll
    for (int i = 0; i < 8; ++i) {
        const int c = i * 8 + (tid >> 5);
        const int t = (tid & 31) * 4;
        float4 o = { sm.zt[c][t], sm.zt[c][t + 1],
                     sm.zt[c][t + 2], sm.zt[c][t + 3] };
        *(float4*)(obase + (size_t)c * L + t0 + t) = o;
    }
}

extern "C" void kernel_launch(void* const* d_in, const int* in_sizes, int n_in,
                              void* d_out, int out_size, void* d_ws, size_t ws_size,
                              hipStream_t stream) {
    const float* qkv = (const float*)d_in[0];
    float* out = (float*)d_out;
    if (ws_size >= (size_t)WS_BYTES) {
        _Float16* ws = (_Float16*)d_ws;
        prepass_kernel<<<4096, 256, 0, stream>>>(qkv, ws);
        // 128 heads x 4 t-tiles of 256 = 512 blocks (2 per CU)
        attn_kernel<<<512, 256, 0, stream>>>(qkv, ws, out);
    } else {
        qkv_attn_fallback<<<1024, 256, 0, stream>>>(qkv, out);
    }
}